// Round 10
// baseline (281.116 us; speedup 1.0000x reference)
//
#include <hip/hip_runtime.h>

#define NROW 524288
#define KDIM 66
#define NSEG 65
#define NB   2048
#define PART_STRIDE 12

// ws layout: [0, NB*12*8): double partials (10 h1 accs, sum_soc, sum_soc2)

// ---------------------------------------------------------------------------
// Compile-time precomputation of everything input-independent (round-4 fix:
// runtime version spilled ~5.3 KB/thread to scratch, 93.7 us).
// ---------------------------------------------------------------------------
struct Pre {
    float  xk[KDIM];
    float  dxf[NSEG];
    double av[KDIM];      // A^T lower diag
    double winv[KDIM];    // 1 / pivot
    double cp[KDIM];      // Thomas upper coeff
    double dxinv[NSEG];   // 1 / dx  (f64)
    double d3[NSEG];      // 3 * dx  (f64)
    double pp, qq, r1, r2;
};

constexpr Pre make_pre() {
    Pre p{};
    for (int k = 0; k < KDIM; ++k) p.xk[k] = (float)((1.0 / 65.0) * (double)k);
    p.xk[KDIM - 1] = 1.0f;
    for (int k = 0; k < NSEG; ++k) p.dxf[k] = p.xk[k + 1] - p.xk[k];

    double d02 = (double)(p.xk[2] - p.xk[0]);
    double dl  = (double)(p.xk[KDIM - 1] - p.xk[KDIM - 3]);

    double bv[KDIM] = {};
    double cv[KDIM] = {};
    bv[0] = (double)p.dxf[1];
    bv[KDIM - 1] = (double)p.dxf[KDIM - 3];
    for (int i = 1; i < KDIM - 1; ++i)
        bv[i] = 2.0 * ((double)p.dxf[i] + (double)p.dxf[i - 1]);
    p.av[0] = 0.0;
    p.av[1] = d02;
    for (int i = 2; i < KDIM; ++i) p.av[i] = (double)p.dxf[i - 2];
    for (int i = 0; i < KDIM - 2; ++i) cv[i] = (double)p.dxf[i + 1];
    cv[KDIM - 2] = dl;
    cv[KDIM - 1] = 0.0;

    double w = bv[0];
    p.winv[0] = 1.0 / w;
    p.cp[0]   = cv[0] / w;
    for (int i = 1; i < KDIM; ++i) {
        w = bv[i] - p.av[i] * p.cp[i - 1];
        p.winv[i] = 1.0 / w;
        p.cp[i]   = cv[i] / w;
    }
    for (int m = 0; m < NSEG; ++m) {
        p.dxinv[m] = 1.0 / (double)p.dxf[m];
        p.d3[m]    = 3.0 * (double)p.dxf[m];
    }
    p.pp = ((double)p.dxf[0] + 2.0 * d02) * (double)p.dxf[1] / d02;
    p.qq = (double)p.dxf[0] * (double)p.dxf[0] / d02;
    p.r1 = (double)p.dxf[64] * (double)p.dxf[64] / dl;
    p.r2 = (2.0 * dl + (double)p.dxf[64]) * (double)p.dxf[63] / dl;
    return p;
}

__device__ constexpr Pre PRE = make_pre();

// ---------------------------------------------------------------------------
// Main kernel.
// Round-7 PMC: per-thread-row reads = 64 L1 lines per load instruction
// (264 B lane stride) -> VMEM-transaction-bound, 88 us @ 14% HBM.
// Fix: 8-lane groups per row. Lane g of group r reads float2 chunks
// {g,8+g,16+g,24+g} of the row (8 lanes cover 64 contiguous bytes ->
// ~15 lines/instr instead of 64), tail chunk 32 by g==0; 3-level shfl_xor
// finishes the dot; nd bounced via same-wave LDS back to thread<->row order;
// then the verified phase-2 (coalesced W1/soc, f64 accumulate, reduce).
// Per-block weight derivation in threads 0/1 (round-7, verified; no fences —
// round 6 showed grid-sync fences cost ~440 us).
// ---------------------------------------------------------------------------
__global__ __launch_bounds__(256) void main_kernel(
    const float* __restrict__ x, const float* __restrict__ soc,
    const float* __restrict__ W1,
    const float* __restrict__ ti, const float* __restrict__ tj,
    float* __restrict__ out_ndis, double* __restrict__ partials)
{
    __shared__ __align__(16) float wi_s[KDIM];
    __shared__ __align__(16) float wj_s[KDIM];
    __shared__ double dp_s[2][KDIM];
    __shared__ double z_s[2][KDIM];
    __shared__ float nd_s[4][64];
    __shared__ double red[4][12];

    const int tid = threadIdx.x;

    // ---- per-block weight derivation (threads 0,1) ----
    if (tid < 2) {
        const float t = (tid == 0) ? ti[0] : tj[0];
        float* wo = (tid == 0) ? wi_s : wj_s;

        int kk = 0;
        float xkk = PRE.xk[0], xkk1 = PRE.xk[1];
#pragma unroll
        for (int k = 0; k <= KDIM - 2; ++k) {
            if (PRE.xk[k] <= t) { kk = k; xkk = PRE.xk[k]; xkk1 = PRE.xk[k + 1]; }
        }

        const double h  = (double)(xkk1 - xkk);
        const double u  = (double)(t - xkk);
        const double u2 = u * u, u3 = u2 * u, h2 = h * h;
        const double alpha = u3 / h2 - 2.0 * u2 / h + u;
        const double beta  = u3 / h2 - u2 / h;
        const double gamma = 3.0 * u2 / h - 2.0 * u3 / h2;

        double dpv = 0.0;
#pragma unroll
        for (int i = 0; i < KDIM; ++i) {
            double rhs = (i == kk) ? alpha : ((i == kk + 1) ? beta : 0.0);
            dpv = (rhs - PRE.av[i] * dpv) * PRE.winv[i];
            dp_s[tid][i] = dpv;
        }

        double zv = dp_s[tid][KDIM - 1];
        z_s[tid][KDIM - 1] = zv;
#pragma unroll
        for (int i = KDIM - 2; i >= 0; --i) {
            zv = dp_s[tid][i] - PRE.cp[i] * zv;
            z_s[tid][i] = zv;
        }

        const double z0  = z_s[tid][0];
        const double z65 = z_s[tid][KDIM - 1];
        double c = z0 * PRE.pp;
        double carryW = 0.0;
#pragma unroll
        for (int j = 1; j <= 64; ++j) {
            const double zj = z_s[tid][j];
            double full = c + zj * PRE.d3[j];
            if (j - 1 == kk) full += gamma;
            if (j == 64)     full += z65 * PRE.r1;
            const double w = full * PRE.dxinv[j - 1];
            double wy = carryW - w;
            if (j - 1 == kk) wy += 1.0;
            wo[j - 1] = (float)wy;
            carryW = w;
            c = zj * PRE.d3[j - 1];
            if (j == 1) c += z0 * PRE.qq;
        }
        double full64 = c + z65 * PRE.r2;
        if (kk == 64) full64 += gamma;
        const double w64 = full64 * PRE.dxinv[64];
        double wy64 = carryW - w64;
        if (kk == 64) wy64 += 1.0;
        wo[64] = (float)wy64;
        wo[65] = (float)w64;
    }
    __syncthreads();

    // ---- phase 1: cooperative row dots (8 lanes per row) ----
    const int w    = tid >> 6;         // wave id in block
    const int lane = tid & 63;
    const int g    = lane & 7;         // lane within group
    const int r    = lane >> 3;        // group id (0..7)
    const int wbase = blockIdx.x * 256 + w * 64;

    const float2* wi2 = (const float2*)wi_s;
    const float2* wj2 = (const float2*)wj_s;
    // hoisted per-lane weights (loop-invariant: same g every iteration)
    const float2 ai0 = wi2[g], ai1 = wi2[8 + g], ai2 = wi2[16 + g], ai3 = wi2[24 + g];
    const float2 aj0 = wj2[g], aj1 = wj2[8 + g], aj2 = wj2[16 + g], aj3 = wj2[24 + g];
    const float2 ai4 = wi2[32], aj4 = wj2[32];   // tail weights (used by g==0)

#pragma unroll
    for (int i = 0; i < 8; ++i) {
        const int row = wbase + i * 8 + r;
        const float2* __restrict__ rp = (const float2*)(x + (size_t)row * KDIM);
        const float2 v0 = rp[g];
        const float2 v1 = rp[8 + g];
        const float2 v2 = rp[16 + g];
        const float2 v3 = rp[24 + g];

        float si = v0.x * ai0.x;
        si = fmaf(v0.y, ai0.y, si);
        si = fmaf(v1.x, ai1.x, si); si = fmaf(v1.y, ai1.y, si);
        si = fmaf(v2.x, ai2.x, si); si = fmaf(v2.y, ai2.y, si);
        si = fmaf(v3.x, ai3.x, si); si = fmaf(v3.y, ai3.y, si);
        float sj = v0.x * aj0.x;
        sj = fmaf(v0.y, aj0.y, sj);
        sj = fmaf(v1.x, aj1.x, sj); sj = fmaf(v1.y, aj1.y, sj);
        sj = fmaf(v2.x, aj2.x, sj); sj = fmaf(v2.y, aj2.y, sj);
        sj = fmaf(v3.x, aj3.x, sj); sj = fmaf(v3.y, aj3.y, sj);

        if (g == 0) {                        // ragged 33rd float2 (floats 64,65)
            const float2 v4 = rp[32];
            si = fmaf(v4.x, ai4.x, si); si = fmaf(v4.y, ai4.y, si);
            sj = fmaf(v4.x, aj4.x, sj); sj = fmaf(v4.y, aj4.y, sj);
        }

        // 3-level butterfly within the 8-lane group
        si += __shfl_xor(si, 1); si += __shfl_xor(si, 2); si += __shfl_xor(si, 4);
        sj += __shfl_xor(sj, 1); sj += __shfl_xor(sj, 2); sj += __shfl_xor(sj, 4);

        if (g == 0)
            nd_s[w][i * 8 + r] = (si - sj) / (si + sj);
    }
    // same-wave LDS write->read: compiler-inserted lgkmcnt ordering suffices.

    // ---- phase 2 (round-5/7 verified): coalesced W1/soc, f64 accumulate ----
    const int n = blockIdx.x * 256 + tid;    // == wbase + lane
    const float nd = nd_s[w][lane];

    float w1v[10];
#pragma unroll
    for (int o = 0; o < 10; ++o) w1v[o] = W1[(size_t)o * NROW + n];
    const float socv = soc[n];

    out_ndis[n] = nd;

    const double ndd = (double)nd;
    double acc[12];
#pragma unroll
    for (int o = 0; o < 10; ++o) acc[o] = (double)w1v[o] * ndd;
    const double sv = (double)socv;
    acc[10] = sv;
    acc[11] = sv * sv;

#pragma unroll
    for (int o = 0; o < 12; ++o) {
        double v = acc[o];
#pragma unroll
        for (int off = 32; off > 0; off >>= 1) v += __shfl_down(v, off, 64);
        acc[o] = v;
    }
    if (lane == 0) {
#pragma unroll
        for (int o = 0; o < 12; ++o) red[w][o] = acc[o];
    }
    __syncthreads();
    if (tid < 12) {
        double s = red[0][tid] + red[1][tid] + red[2][tid] + red[3][tid];
        partials[(size_t)blockIdx.x * PART_STRIDE + tid] = s;
    }
}

// ---------------------------------------------------------------------------
// Finalize (own launch — implicit inter-kernel ordering, no fences):
// reduce 2048x12 partials, b1 / leaky-relu / W2 / b2, closed-form loss
// N*s^2 - 2*s*sum(soc) + sum(soc^2).
// ---------------------------------------------------------------------------
__global__ void finalize_kernel(const double* __restrict__ partials,
                                const float* __restrict__ b1,
                                const float* __restrict__ W2,
                                const float* __restrict__ b2,
                                float* __restrict__ out)
{
    __shared__ double red[16][16];
    __shared__ double totals[12];
    int tid = threadIdx.x;
    int o = tid & 15, g = tid >> 4;     // 16 groups x 16 slots (12 used)
    double s = 0.0;
    if (o < 12) {
        for (int b = g; b < NB; b += 16)
            s += partials[(size_t)b * PART_STRIDE + o];
    }
    red[g][o] = s;
    __syncthreads();
    if (tid < 12) {
        double tot = 0.0;
        for (int g2 = 0; g2 < 16; ++g2) tot += red[g2][tid];
        totals[tid] = tot;
    }
    __syncthreads();
    if (tid == 0) {
        double acc = 0.0;
#pragma unroll
        for (int o2 = 0; o2 < 10; ++o2) {
            double h1 = totals[o2] + (double)b1[o2];
            h1 = (h1 > 0.0) ? h1 : 0.01 * h1;
            acc += (double)W2[o2] * h1;
        }
        double shat = acc + (double)b2[0];
        out[0] = (float)shat;
        double ssum = totals[10], ssum2 = totals[11];
        double loss = (double)NROW * shat * shat - 2.0 * shat * ssum + ssum2;
        out[1 + NROW] = (float)loss;
    }
}

extern "C" void kernel_launch(void* const* d_in, const int* in_sizes, int n_in,
                              void* d_out, int out_size, void* d_ws, size_t ws_size,
                              hipStream_t stream) {
    const float* x   = (const float*)d_in[0];
    const float* soc = (const float*)d_in[1];
    const float* ti  = (const float*)d_in[2];
    const float* tj  = (const float*)d_in[3];
    const float* W1  = (const float*)d_in[4];
    const float* b1  = (const float*)d_in[5];
    const float* W2  = (const float*)d_in[6];
    const float* b2  = (const float*)d_in[7];
    float* out = (float*)d_out;

    double* partials = (double*)d_ws;

    main_kernel<<<NB, 256, 0, stream>>>(x, soc, W1, ti, tj, out + 1, partials);
    finalize_kernel<<<1, 256, 0, stream>>>(partials, b1, W2, b2, out);
}